// Round 5
// baseline (415.741 us; speedup 1.0000x reference)
//
#include <hip/hip_runtime.h>
#include <hip/hip_bf16.h>

// Problem constants (match reference)
#define N_ATOMS 20000
#define N_EDGES 400000
#define NCH 4
#define F_IN 128
#define S_OUT 32

// ---------- helpers ----------
__device__ __forceinline__ float silu_f(float v) { return v / (1.f + __expf(-v)); }

__device__ __forceinline__ int wave_iscan(int v, int l) {
#pragma unroll
    for (int off = 1; off < 64; off <<= 1) {
        int t = __shfl_up(v, off);
        if (l >= off) v += t;
    }
    return v;
}

// ---------- fill ----------
__global__ void fill_kernel(float* __restrict__ p, int n, float v) {
    int i = blockIdx.x * blockDim.x + threadIdx.x;
    int stride = gridDim.x * blockDim.x;
    for (; i < n; i += stride) p[i] = v;
}

// ---------- LayerNorm over last dim (128) ----------
__global__ __launch_bounds__(256) void ln_kernel(const float* __restrict__ x,
                                                 const float* __restrict__ gamma,
                                                 const float* __restrict__ beta,
                                                 float* __restrict__ out) {
    int row = blockIdx.x * 4 + (threadIdx.x >> 6);  // row in [0, N*C)
    int l = threadIdx.x & 63;
    const float* xr = x + (size_t)row * F_IN;
    float v0 = xr[l], v1 = xr[l + 64];
    float s = v0 + v1, sq = v0 * v0 + v1 * v1;
#pragma unroll
    for (int off = 32; off; off >>= 1) {
        s += __shfl_xor(s, off);
        sq += __shfl_xor(sq, off);
    }
    float mu = s * (1.f / 128.f);
    float var = sq * (1.f / 128.f) - mu * mu;
    float rs = rsqrtf(var + 1e-5f);
    float* orow = out + (size_t)row * F_IN;
    orow[l]      = (v0 - mu) * rs * gamma[l]      + beta[l];
    orow[l + 64] = (v1 - mu) * rs * gamma[l + 64] + beta[l + 64];
}

// ---------- per-channel projection: out[n,c,o]=sum_k in[n,c,k]W[c,k,o]; plus attn dots ----------
template <int FIN, bool SILU_IN, bool ATT>
__global__ __launch_bounds__(256) void proj_kernel(const float* __restrict__ in,
                                                   const float* __restrict__ W,
                                                   const float* __restrict__ a_src,
                                                   const float* __restrict__ a_dst,
                                                   float* __restrict__ out,
                                                   float* __restrict__ es,
                                                   float* __restrict__ ed) {
    __shared__ float Wl[FIN * 64];
    __shared__ float inl[32 * FIN];
    const int tid = threadIdx.x;
    const int n0 = blockIdx.x * 32;
    const int o = tid & 63;
    const int w = tid >> 6;

    for (int c = 0; c < NCH; ++c) {
        for (int i = tid; i < FIN * 64; i += 256) Wl[i] = W[c * FIN * 64 + i];
        for (int i = tid; i < 32 * FIN; i += 256) {
            int nl = i / FIN, k = i - nl * FIN;
            float v = in[(size_t)(n0 + nl) * (NCH * FIN) + c * FIN + k];
            if (SILU_IN) v = silu_f(v);
            inl[i] = v;
        }
        __syncthreads();

        float as = 0.f, ad = 0.f;
        if (ATT) { as = a_src[c * 64 + o]; ad = a_dst[c * 64 + o]; }

        float acc[8];
#pragma unroll
        for (int i = 0; i < 8; ++i) acc[i] = 0.f;
#pragma unroll 4
        for (int k = 0; k < FIN; ++k) {
            float wv = Wl[k * 64 + o];
#pragma unroll
            for (int i = 0; i < 8; ++i) acc[i] += inl[(w * 8 + i) * FIN + k] * wv;
        }
#pragma unroll
        for (int i = 0; i < 8; ++i) {
            int n = n0 + w * 8 + i;
            out[(size_t)n * 256 + c * 64 + o] = acc[i];
            if (ATT) {
                float vs = acc[i] * as, vd = acc[i] * ad;
#pragma unroll
                for (int off = 32; off; off >>= 1) {
                    vs += __shfl_xor(vs, off);
                    vd += __shfl_xor(vd, off);
                }
                if (o == 0) { es[n * NCH + c] = vs; ed[n * NCH + c] = vd; }
            }
        }
        __syncthreads();
    }
}

// ---------- CSR build: histogram -> hierarchical scan -> scatter ----------
__global__ void hist_kernel(const int* __restrict__ ei, int* __restrict__ cnt, int E) {
    int e = blockIdx.x * 256 + threadIdx.x;
    if (e < E) atomicAdd(&cnt[ei[E + e]], 1);
}

__global__ __launch_bounds__(256) void scan_l1_kernel(const int* __restrict__ cnt,
                                                      int* __restrict__ rowp,
                                                      int* __restrict__ bsum, int n) {
    int i = blockIdx.x * 256 + threadIdx.x;
    int l = threadIdx.x & 63, w = threadIdx.x >> 6;
    int v = (i < n) ? cnt[i] : 0;
    int incl = wave_iscan(v, l);
    __shared__ int wsum[4];
    if (l == 63) wsum[w] = incl;
    __syncthreads();
    int add = 0;
#pragma unroll
    for (int j = 0; j < 4; ++j) add += (j < w) ? wsum[j] : 0;
    if (i < n) rowp[i] = add + incl - v;
    if (threadIdx.x == 255) bsum[blockIdx.x] = add + incl;
}

__global__ __launch_bounds__(256) void scan_l2_kernel(const int* __restrict__ bsum,
                                                      int* __restrict__ boff,
                                                      int* __restrict__ rowp_n, int nb,
                                                      float* __restrict__ out_zero) {
    int i = threadIdx.x;
    if (i < S_OUT) out_zero[i] = 0.f;  // fused energies zero-init
    int l = i & 63, w = i >> 6;
    int v = (i < nb) ? bsum[i] : 0;
    int incl = wave_iscan(v, l);
    __shared__ int wsum[4];
    if (l == 63) wsum[w] = incl;
    __syncthreads();
    int add = 0;
#pragma unroll
    for (int j = 0; j < 4; ++j) add += (j < w) ? wsum[j] : 0;
    if (i < nb) boff[i] = add + incl - v;
    if (i == nb - 1) *rowp_n = add + incl;
}

__global__ __launch_bounds__(256) void scan_l3_kernel(int* __restrict__ rowp,
                                                      const int* __restrict__ boff, int n) {
    int i = blockIdx.x * 256 + threadIdx.x;
    if (i < n) rowp[i] += boff[blockIdx.x];
}

__global__ void scatter_kernel(const int* __restrict__ ei, const int* __restrict__ rowp,
                               int* __restrict__ fill, int* __restrict__ csr_src, int E) {
    int e = blockIdx.x * 256 + threadIdx.x;
    if (e < E) {
        int d = ei[E + e];
        int pos = rowp[d] + atomicAdd(&fill[d], 1);
        csr_src[pos] = ei[e];
    }
}

// ---------- fused GAT aggregation (gather side): softmax + weighted sum ----------
// one block per dst node; 4 waves = 4 channels; 64 lanes dual-role (edges / features)
template <bool SILU_OUT>
__global__ __launch_bounds__(256) void gat_gather_kernel(const int* __restrict__ rowp,
                                                         const int* __restrict__ csr_src,
                                                         const float* __restrict__ es,
                                                         const float* __restrict__ ed,
                                                         const float* __restrict__ h,
                                                         float* __restrict__ out) {
    int d = blockIdx.x;
    int c = threadIdx.x >> 6, o = threadIdx.x & 63;
    int r0 = rowp[d], r1 = rowp[d + 1];
    __shared__ int   ssrc[NCH][64];
    __shared__ float sex[NCH][64];
    float edc = ed[d * NCH + c];
    float m = -1e30f, den = 0.f, acc = 0.f;
    for (int base = r0; base < r1; base += 64) {
        int len = min(64, r1 - base);
        // phase A: lanes = edges
        float logit = -1e30f;
        int s = 0;
        if (o < len) {
            s = csr_src[base + o];
            float v = es[s * NCH + c] + edc;
            logit = v >= 0.f ? v : 0.2f * v;
        }
        float cm = logit;
#pragma unroll
        for (int off = 32; off; off >>= 1) cm = fmaxf(cm, __shfl_xor(cm, off));
        float nm = fmaxf(m, cm);
        float resc = __expf(m - nm);           // 0 on first chunk
        float ex = (o < len) ? __expf(logit - nm) : 0.f;
        float cs = ex;
#pragma unroll
        for (int off = 32; off; off >>= 1) cs += __shfl_xor(cs, off);
        den = den * resc + cs;
        acc *= resc;
        m = nm;
        ssrc[c][o] = s;
        sex[c][o] = ex;
        __syncthreads();
        // phase B: lanes = features
        for (int jj = 0; jj < len; ++jj) {
            int sj = ssrc[c][jj];
            acc += sex[c][jj] * h[(size_t)sj * 256 + c * 64 + o];
        }
        __syncthreads();
    }
    float r = acc / (den + 1e-16f);
    out[(size_t)d * 256 + c * 64 + o] = SILU_OUT ? silu_f(r) : r;
}

// ---------- MLP layer 1: register weights + uniform (scalar) input loads ----------
// wave = channel; in is pre-silu'd conv2 output [N,256]; writes silu(t1) [C][N][64]
__global__ __launch_bounds__(256) void mlp1_kernel(const float* __restrict__ in,
                                                   const float* __restrict__ W1,
                                                   float* __restrict__ t1g) {
    const int o = threadIdx.x & 63;
    const int c = threadIdx.x >> 6;
    const int n0 = blockIdx.x * 16;
    float w1r[64];
#pragma unroll
    for (int j = 0; j < 64; ++j) w1r[j] = W1[c * 4096 + j * 64 + o];
    for (int nl = 0; nl < 16; ++nl) {
        int node = n0 + nl;
        const float* __restrict__ a = in + (size_t)node * 256 + c * 64;
        float a0 = 0.f, a1 = 0.f, a2 = 0.f, a3 = 0.f;
#pragma unroll
        for (int k = 0; k < 64; k += 4) {
            a0 = fmaf(a[k], w1r[k], a0);
            a1 = fmaf(a[k + 1], w1r[k + 1], a1);
            a2 = fmaf(a[k + 2], w1r[k + 2], a2);
            a3 = fmaf(a[k + 3], w1r[k + 3], a3);
        }
        t1g[((size_t)c * N_ATOMS + node) * 64 + o] = silu_f((a0 + a1) + (a2 + a3));
    }
}

// ---------- MLP layers 2+3 + channel/structure reduction ----------
__global__ __launch_bounds__(256) void mlp2_kernel(const float* __restrict__ t1g,
                                                   const float* __restrict__ W2,
                                                   const float* __restrict__ W3,
                                                   const int* __restrict__ bat,
                                                   float* __restrict__ out) {
    const int o = threadIdx.x & 63;
    const int c = threadIdx.x >> 6;
    const int o2 = o & 31;
    const int n0 = blockIdx.x * 16;
    float w2r[64];
#pragma unroll
    for (int j = 0; j < 64; ++j) w2r[j] = W2[c * 2048 + j * 32 + o2];
    float w3v = (o < 32) ? W3[c * 32 + o2] : 0.f;
    float ysum = 0.f;
    int bcur = bat[n0];
    for (int nl = 0; nl < 16; ++nl) {
        int node = n0 + nl;
        const float* __restrict__ a = t1g + ((size_t)c * N_ATOMS + node) * 64;
        float a0 = 0.f, a1 = 0.f, a2 = 0.f, a3 = 0.f;
#pragma unroll
        for (int k = 0; k < 64; k += 4) {
            a0 = fmaf(a[k], w2r[k], a0);
            a1 = fmaf(a[k + 1], w2r[k + 1], a1);
            a2 = fmaf(a[k + 2], w2r[k + 2], a2);
            a3 = fmaf(a[k + 3], w2r[k + 3], a3);
        }
        float t = silu_f((a0 + a1) + (a2 + a3)) * w3v;
#pragma unroll
        for (int off = 32; off; off >>= 1) t += __shfl_xor(t, off);
        int b = bat[node];
        if (b != bcur) {
            if (o == 0) atomicAdd(out + bcur, ysum * 0.025f);
            ysum = 0.f;
            bcur = b;
        }
        ysum += t;
    }
    if (o == 0) atomicAdd(out + bcur, ysum * 0.025f);  // /sqrt(4)/20
}

extern "C" void kernel_launch(void* const* d_in, const int* in_sizes, int n_in,
                              void* d_out, int out_size, void* d_ws, size_t ws_size,
                              hipStream_t stream) {
    const float* x     = (const float*)d_in[0];
    const int*   ei    = (const int*)d_in[1];
    const int*   bat   = (const int*)d_in[2];
    const float* gamma = (const float*)d_in[3];
    const float* beta  = (const float*)d_in[4];
    const float* Wc1   = (const float*)d_in[5];
    const float* as1   = (const float*)d_in[6];
    const float* ad1   = (const float*)d_in[7];
    const float* Wc2   = (const float*)d_in[8];
    const float* as2   = (const float*)d_in[9];
    const float* ad2   = (const float*)d_in[10];
    const float* Wn1   = (const float*)d_in[11];
    const float* Wn2   = (const float*)d_in[12];
    const float* Wout  = (const float*)d_in[13];
    float* out = (float*)d_out;

    // workspace layout (floats)
    float* A    = (float*)d_ws;            // 10.24M: LN out [N,C,128]; reused for conv outs
    float* B    = A + 10240000;            // 5.12M : proj output h [N,C,64]; reused for t1g
    float* es   = B + 5120000;             // 80k
    float* ed   = es + 80000;              // 80k
    int* rowp   = (int*)(ed + 80000);      // 20001 (pad 20004)
    int* cnt    = rowp + 20004;            // 20000
    int* fillc  = cnt + 20000;             // 20000
    int* csr    = fillc + 20000;           // 400000
    int* bsum   = csr + 400000;            // 128
    int* boff   = bsum + 128;              // 128
    float* C1   = A;                       // conv1 out [N,C,64]
    float* C2   = A + 5120000;             // conv2 out (silu'd) [N,C,64]
    float* t1g  = B;                       // mlp hidden [C][N][64] (B dead after gather2)

    dim3 blk(256);
    const int NB = (N_ATOMS + 255) / 256;  // 79

    // ---- CSR build (graph is shared by both convs) ----
    fill_kernel<<<80, blk, 0, stream>>>((float*)cnt, 40000, 0.f);  // cnt + fillc (adjacent)
    hist_kernel<<<(N_EDGES + 255) / 256, blk, 0, stream>>>(ei, cnt, N_EDGES);
    scan_l1_kernel<<<NB, blk, 0, stream>>>(cnt, rowp, bsum, N_ATOMS);
    scan_l2_kernel<<<1, blk, 0, stream>>>(bsum, boff, rowp + N_ATOMS, NB, out);
    scan_l3_kernel<<<NB, blk, 0, stream>>>(rowp, boff, N_ATOMS);
    scatter_kernel<<<(N_EDGES + 255) / 256, blk, 0, stream>>>(ei, rowp, fillc, csr, N_EDGES);

    // ---- LayerNorm ----
    ln_kernel<<<N_ATOMS * NCH / 4, blk, 0, stream>>>(x, gamma, beta, A);

    // ---- conv1 ----
    proj_kernel<128, false, true><<<N_ATOMS / 32, blk, 0, stream>>>(A, Wc1, as1, ad1, B, es, ed);
    gat_gather_kernel<false><<<N_ATOMS, blk, 0, stream>>>(rowp, csr, es, ed, B, C1);

    // ---- conv2 (silu fused on load; silu fused on output for MLP) ----
    proj_kernel<64, true, true><<<N_ATOMS / 32, blk, 0, stream>>>(C1, Wc2, as2, ad2, B, es, ed);
    gat_gather_kernel<true><<<N_ATOMS, blk, 0, stream>>>(rowp, csr, es, ed, B, C2);

    // ---- MLP head: register-weight scalar-FMA kernels ----
    mlp1_kernel<<<N_ATOMS / 16, blk, 0, stream>>>(C2, Wn1, t1g);
    mlp2_kernel<<<N_ATOMS / 16, blk, 0, stream>>>(t1g, Wn2, Wout, bat, out);
}

// Round 6
// 374.005 us; speedup vs baseline: 1.1116x; 1.1116x over previous
//
#include <hip/hip_runtime.h>
#include <hip/hip_bf16.h>

// Problem constants (match reference)
#define N_ATOMS 20000
#define N_EDGES 400000
#define NCH 4
#define F_IN 128
#define S_OUT 32

// ---------- helpers ----------
__device__ __forceinline__ float silu_f(float v) { return v / (1.f + __expf(-v)); }

__device__ __forceinline__ float bcast_lane(float v, int k) {
    return __uint_as_float(__builtin_amdgcn_readlane(__float_as_uint(v), k));
}

__device__ __forceinline__ int wave_iscan(int v, int l) {
#pragma unroll
    for (int off = 1; off < 64; off <<= 1) {
        int t = __shfl_up(v, off);
        if (l >= off) v += t;
    }
    return v;
}

// ---------- fill ----------
__global__ void fill_kernel(float* __restrict__ p, int n, float v) {
    int i = blockIdx.x * blockDim.x + threadIdx.x;
    int stride = gridDim.x * blockDim.x;
    for (; i < n; i += stride) p[i] = v;
}

// ---------- LayerNorm over last dim (128) ----------
__global__ __launch_bounds__(256) void ln_kernel(const float* __restrict__ x,
                                                 const float* __restrict__ gamma,
                                                 const float* __restrict__ beta,
                                                 float* __restrict__ out) {
    int row = blockIdx.x * 4 + (threadIdx.x >> 6);  // row in [0, N*C)
    int l = threadIdx.x & 63;
    const float* xr = x + (size_t)row * F_IN;
    float v0 = xr[l], v1 = xr[l + 64];
    float s = v0 + v1, sq = v0 * v0 + v1 * v1;
#pragma unroll
    for (int off = 32; off; off >>= 1) {
        s += __shfl_xor(s, off);
        sq += __shfl_xor(sq, off);
    }
    float mu = s * (1.f / 128.f);
    float var = sq * (1.f / 128.f) - mu * mu;
    float rs = rsqrtf(var + 1e-5f);
    float* orow = out + (size_t)row * F_IN;
    orow[l]      = (v0 - mu) * rs * gamma[l]      + beta[l];
    orow[l + 64] = (v1 - mu) * rs * gamma[l + 64] + beta[l + 64];
}

// ---------- per-channel projection: out[n,c,o]=sum_k in[n,c,k]W[c,k,o]; plus attn dots ----------
template <int FIN, bool SILU_IN, bool ATT>
__global__ __launch_bounds__(256) void proj_kernel(const float* __restrict__ in,
                                                   const float* __restrict__ W,
                                                   const float* __restrict__ a_src,
                                                   const float* __restrict__ a_dst,
                                                   float* __restrict__ out,
                                                   float* __restrict__ es,
                                                   float* __restrict__ ed) {
    __shared__ float Wl[FIN * 64];
    __shared__ float inl[32 * FIN];
    const int tid = threadIdx.x;
    const int n0 = blockIdx.x * 32;
    const int o = tid & 63;
    const int w = tid >> 6;

    for (int c = 0; c < NCH; ++c) {
        for (int i = tid; i < FIN * 64; i += 256) Wl[i] = W[c * FIN * 64 + i];
        for (int i = tid; i < 32 * FIN; i += 256) {
            int nl = i / FIN, k = i - nl * FIN;
            float v = in[(size_t)(n0 + nl) * (NCH * FIN) + c * FIN + k];
            if (SILU_IN) v = silu_f(v);
            inl[i] = v;
        }
        __syncthreads();

        float as = 0.f, ad = 0.f;
        if (ATT) { as = a_src[c * 64 + o]; ad = a_dst[c * 64 + o]; }

        float acc[8];
#pragma unroll
        for (int i = 0; i < 8; ++i) acc[i] = 0.f;
#pragma unroll 4
        for (int k = 0; k < FIN; ++k) {
            float wv = Wl[k * 64 + o];
#pragma unroll
            for (int i = 0; i < 8; ++i) acc[i] += inl[(w * 8 + i) * FIN + k] * wv;
        }
#pragma unroll
        for (int i = 0; i < 8; ++i) {
            int n = n0 + w * 8 + i;
            out[(size_t)n * 256 + c * 64 + o] = acc[i];
            if (ATT) {
                float vs = acc[i] * as, vd = acc[i] * ad;
#pragma unroll
                for (int off = 32; off; off >>= 1) {
                    vs += __shfl_xor(vs, off);
                    vd += __shfl_xor(vd, off);
                }
                if (o == 0) { es[n * NCH + c] = vs; ed[n * NCH + c] = vd; }
            }
        }
        __syncthreads();
    }
}

// ---------- CSR build: histogram -> hierarchical scan -> scatter ----------
__global__ void hist_kernel(const int* __restrict__ ei, int* __restrict__ cnt, int E) {
    int e = blockIdx.x * 256 + threadIdx.x;
    if (e < E) atomicAdd(&cnt[ei[E + e]], 1);
}

__global__ __launch_bounds__(256) void scan_l1_kernel(const int* __restrict__ cnt,
                                                      int* __restrict__ rowp,
                                                      int* __restrict__ bsum, int n) {
    int i = blockIdx.x * 256 + threadIdx.x;
    int l = threadIdx.x & 63, w = threadIdx.x >> 6;
    int v = (i < n) ? cnt[i] : 0;
    int incl = wave_iscan(v, l);
    __shared__ int wsum[4];
    if (l == 63) wsum[w] = incl;
    __syncthreads();
    int add = 0;
#pragma unroll
    for (int j = 0; j < 4; ++j) add += (j < w) ? wsum[j] : 0;
    if (i < n) rowp[i] = add + incl - v;
    if (threadIdx.x == 255) bsum[blockIdx.x] = add + incl;
}

__global__ __launch_bounds__(256) void scan_l2_kernel(const int* __restrict__ bsum,
                                                      int* __restrict__ boff,
                                                      int* __restrict__ rowp_n, int nb,
                                                      float* __restrict__ out_zero) {
    int i = threadIdx.x;
    if (i < S_OUT) out_zero[i] = 0.f;  // fused energies zero-init
    int l = i & 63, w = i >> 6;
    int v = (i < nb) ? bsum[i] : 0;
    int incl = wave_iscan(v, l);
    __shared__ int wsum[4];
    if (l == 63) wsum[w] = incl;
    __syncthreads();
    int add = 0;
#pragma unroll
    for (int j = 0; j < 4; ++j) add += (j < w) ? wsum[j] : 0;
    if (i < nb) boff[i] = add + incl - v;
    if (i == nb - 1) *rowp_n = add + incl;
}

__global__ __launch_bounds__(256) void scan_l3_kernel(int* __restrict__ rowp,
                                                      const int* __restrict__ boff, int n) {
    int i = blockIdx.x * 256 + threadIdx.x;
    if (i < n) rowp[i] += boff[blockIdx.x];
}

__global__ void scatter_kernel(const int* __restrict__ ei, const int* __restrict__ rowp,
                               int* __restrict__ fill, int* __restrict__ csr_src, int E) {
    int e = blockIdx.x * 256 + threadIdx.x;
    if (e < E) {
        int d = ei[E + e];
        int pos = rowp[d] + atomicAdd(&fill[d], 1);
        csr_src[pos] = ei[e];
    }
}

// ---------- fused GAT aggregation (gather side): softmax + weighted sum ----------
// one block per dst node; 4 waves = 4 channels; 64 lanes dual-role (edges / features)
template <bool SILU_OUT>
__global__ __launch_bounds__(256) void gat_gather_kernel(const int* __restrict__ rowp,
                                                         const int* __restrict__ csr_src,
                                                         const float* __restrict__ es,
                                                         const float* __restrict__ ed,
                                                         const float* __restrict__ h,
                                                         float* __restrict__ out) {
    int d = blockIdx.x;
    int c = threadIdx.x >> 6, o = threadIdx.x & 63;
    int r0 = rowp[d], r1 = rowp[d + 1];
    __shared__ int   ssrc[NCH][64];
    __shared__ float sex[NCH][64];
    float edc = ed[d * NCH + c];
    float m = -1e30f, den = 0.f, acc = 0.f;
    for (int base = r0; base < r1; base += 64) {
        int len = min(64, r1 - base);
        // phase A: lanes = edges
        float logit = -1e30f;
        int s = 0;
        if (o < len) {
            s = csr_src[base + o];
            float v = es[s * NCH + c] + edc;
            logit = v >= 0.f ? v : 0.2f * v;
        }
        float cm = logit;
#pragma unroll
        for (int off = 32; off; off >>= 1) cm = fmaxf(cm, __shfl_xor(cm, off));
        float nm = fmaxf(m, cm);
        float resc = __expf(m - nm);           // 0 on first chunk
        float ex = (o < len) ? __expf(logit - nm) : 0.f;
        float cs = ex;
#pragma unroll
        for (int off = 32; off; off >>= 1) cs += __shfl_xor(cs, off);
        den = den * resc + cs;
        acc *= resc;
        m = nm;
        ssrc[c][o] = s;
        sex[c][o] = ex;
        __syncthreads();
        // phase B: lanes = features
        for (int jj = 0; jj < len; ++jj) {
            int sj = ssrc[c][jj];
            acc += sex[c][jj] * h[(size_t)sj * 256 + c * 64 + o];
        }
        __syncthreads();
    }
    float r = acc / (den + 1e-16f);
    out[(size_t)d * 256 + c * 64 + o] = SILU_OUT ? silu_f(r) : r;
}

// ---------- fused MLP (64->64->32->1) via register weights + readlane broadcast ----------
// wave = channel; lane o holds input feature o of the current node (in is pre-silu'd).
// Layer contractions: acc += readlane(h,k) * w[k] -- no LDS, no per-node weight traffic.
__global__ __launch_bounds__(256) void mlp_fused_kernel(const float* __restrict__ in,
                                                        const float* __restrict__ W1,
                                                        const float* __restrict__ W2,
                                                        const float* __restrict__ W3,
                                                        const int* __restrict__ bat,
                                                        float* __restrict__ out) {
    const int o = threadIdx.x & 63;
    const int c = threadIdx.x >> 6;
    const int o2 = o & 31;
    const int n0 = blockIdx.x * 16;
    float w1r[64];
    float w2r[64];
#pragma unroll
    for (int j = 0; j < 64; ++j) w1r[j] = W1[c * 4096 + j * 64 + o];
#pragma unroll
    for (int j = 0; j < 64; ++j) w2r[j] = W2[c * 2048 + j * 32 + o2];
    float w3v = (o < 32) ? W3[c * 32 + o2] : 0.f;  // lanes >=32 contribute 0

    float ysum = 0.f;
    int bcur = bat[n0];
    for (int nl = 0; nl < 16; ++nl) {
        int node = n0 + nl;
        float h = in[(size_t)node * 256 + c * 64 + o];  // coalesced; already silu'd
        // layer 1: t1[o] = silu(sum_k h[k] * W1[k][o])
        float a0 = 0.f, a1 = 0.f, a2 = 0.f, a3 = 0.f;
#pragma unroll
        for (int k = 0; k < 64; k += 4) {
            a0 = fmaf(bcast_lane(h, k),     w1r[k],     a0);
            a1 = fmaf(bcast_lane(h, k + 1), w1r[k + 1], a1);
            a2 = fmaf(bcast_lane(h, k + 2), w1r[k + 2], a2);
            a3 = fmaf(bcast_lane(h, k + 3), w1r[k + 3], a3);
        }
        float t1 = silu_f((a0 + a1) + (a2 + a3));
        // layer 2: t2[o2] = silu(sum_k t1[k] * W2[k][o2])
        float b0 = 0.f, b1 = 0.f, b2 = 0.f, b3 = 0.f;
#pragma unroll
        for (int k = 0; k < 64; k += 4) {
            b0 = fmaf(bcast_lane(t1, k),     w2r[k],     b0);
            b1 = fmaf(bcast_lane(t1, k + 1), w2r[k + 1], b1);
            b2 = fmaf(bcast_lane(t1, k + 2), w2r[k + 2], b2);
            b3 = fmaf(bcast_lane(t1, k + 3), w2r[k + 3], b3);
        }
        float t = silu_f((b0 + b1) + (b2 + b3)) * w3v;
        // layer 3 + lane reduce (lanes>=32 are zeroed via w3v)
#pragma unroll
        for (int off = 32; off; off >>= 1) t += __shfl_xor(t, off);
        int b = bat[node];
        if (b != bcur) {
            if (o == 0) atomicAdd(out + bcur, ysum * 0.025f);
            ysum = 0.f;
            bcur = b;
        }
        ysum += t;
    }
    if (o == 0) atomicAdd(out + bcur, ysum * 0.025f);  // /sqrt(4)/20
}

extern "C" void kernel_launch(void* const* d_in, const int* in_sizes, int n_in,
                              void* d_out, int out_size, void* d_ws, size_t ws_size,
                              hipStream_t stream) {
    const float* x     = (const float*)d_in[0];
    const int*   ei    = (const int*)d_in[1];
    const int*   bat   = (const int*)d_in[2];
    const float* gamma = (const float*)d_in[3];
    const float* beta  = (const float*)d_in[4];
    const float* Wc1   = (const float*)d_in[5];
    const float* as1   = (const float*)d_in[6];
    const float* ad1   = (const float*)d_in[7];
    const float* Wc2   = (const float*)d_in[8];
    const float* as2   = (const float*)d_in[9];
    const float* ad2   = (const float*)d_in[10];
    const float* Wn1   = (const float*)d_in[11];
    const float* Wn2   = (const float*)d_in[12];
    const float* Wout  = (const float*)d_in[13];
    float* out = (float*)d_out;

    // workspace layout (floats)
    float* A    = (float*)d_ws;            // 10.24M: LN out [N,C,128]; reused for conv outs
    float* B    = A + 10240000;            // 5.12M : proj output h [N,C,64]
    float* es   = B + 5120000;             // 80k
    float* ed   = es + 80000;              // 80k
    int* rowp   = (int*)(ed + 80000);      // 20001 (pad 20004)
    int* cnt    = rowp + 20004;            // 20000
    int* fillc  = cnt + 20000;             // 20000
    int* csr    = fillc + 20000;           // 400000
    int* bsum   = csr + 400000;            // 128
    int* boff   = bsum + 128;              // 128
    float* C1   = A;                       // conv1 out [N,C,64]
    float* C2   = A + 5120000;             // conv2 out (silu'd) [N,C,64]

    dim3 blk(256);
    const int NB = (N_ATOMS + 255) / 256;  // 79

    // ---- CSR build (graph is shared by both convs) ----
    fill_kernel<<<80, blk, 0, stream>>>((float*)cnt, 40000, 0.f);  // cnt + fillc (adjacent)
    hist_kernel<<<(N_EDGES + 255) / 256, blk, 0, stream>>>(ei, cnt, N_EDGES);
    scan_l1_kernel<<<NB, blk, 0, stream>>>(cnt, rowp, bsum, N_ATOMS);
    scan_l2_kernel<<<1, blk, 0, stream>>>(bsum, boff, rowp + N_ATOMS, NB, out);
    scan_l3_kernel<<<NB, blk, 0, stream>>>(rowp, boff, N_ATOMS);
    scatter_kernel<<<(N_EDGES + 255) / 256, blk, 0, stream>>>(ei, rowp, fillc, csr, N_EDGES);

    // ---- LayerNorm ----
    ln_kernel<<<N_ATOMS * NCH / 4, blk, 0, stream>>>(x, gamma, beta, A);

    // ---- conv1 ----
    proj_kernel<128, false, true><<<N_ATOMS / 32, blk, 0, stream>>>(A, Wc1, as1, ad1, B, es, ed);
    gat_gather_kernel<false><<<N_ATOMS, blk, 0, stream>>>(rowp, csr, es, ed, B, C1);

    // ---- conv2 (silu fused on load; silu fused on output for MLP) ----
    proj_kernel<64, true, true><<<N_ATOMS / 32, blk, 0, stream>>>(C1, Wc2, as2, ad2, B, es, ed);
    gat_gather_kernel<true><<<N_ATOMS, blk, 0, stream>>>(rowp, csr, es, ed, B, C2);

    // ---- fused MLP head (register weights + readlane broadcasts) ----
    mlp_fused_kernel<<<N_ATOMS / 16, blk, 0, stream>>>(C2, Wn1, Wn2, Wout, bat, out);
}

// Round 7
// 334.200 us; speedup vs baseline: 1.2440x; 1.1191x over previous
//
#include <hip/hip_runtime.h>
#include <hip/hip_bf16.h>

// Problem constants (match reference)
#define N_ATOMS 20000
#define N_EDGES 400000
#define NCH 4
#define F_IN 128
#define S_OUT 32

// ---------- helpers ----------
__device__ __forceinline__ float silu_f(float v) { return v / (1.f + __expf(-v)); }

__device__ __forceinline__ int wave_iscan(int v, int l) {
#pragma unroll
    for (int off = 1; off < 64; off <<= 1) {
        int t = __shfl_up(v, off);
        if (l >= off) v += t;
    }
    return v;
}

// ---------- fill ----------
__global__ void fill_kernel(float* __restrict__ p, int n, float v) {
    int i = blockIdx.x * blockDim.x + threadIdx.x;
    int stride = gridDim.x * blockDim.x;
    for (; i < n; i += stride) p[i] = v;
}

// ---------- LayerNorm over last dim (128) ----------
__global__ __launch_bounds__(256) void ln_kernel(const float* __restrict__ x,
                                                 const float* __restrict__ gamma,
                                                 const float* __restrict__ beta,
                                                 float* __restrict__ out) {
    int row = blockIdx.x * 4 + (threadIdx.x >> 6);  // row in [0, N*C)
    int l = threadIdx.x & 63;
    const float* xr = x + (size_t)row * F_IN;
    float v0 = xr[l], v1 = xr[l + 64];
    float s = v0 + v1, sq = v0 * v0 + v1 * v1;
#pragma unroll
    for (int off = 32; off; off >>= 1) {
        s += __shfl_xor(s, off);
        sq += __shfl_xor(sq, off);
    }
    float mu = s * (1.f / 128.f);
    float var = sq * (1.f / 128.f) - mu * mu;
    float rs = rsqrtf(var + 1e-5f);
    float* orow = out + (size_t)row * F_IN;
    orow[l]      = (v0 - mu) * rs * gamma[l]      + beta[l];
    orow[l + 64] = (v1 - mu) * rs * gamma[l + 64] + beta[l + 64];
}

// ---------- per-channel projection: out[n,c,o]=sum_k in[n,c,k]W[c,k,o]; plus attn dots ----------
template <int FIN, bool SILU_IN, bool ATT>
__global__ __launch_bounds__(256) void proj_kernel(const float* __restrict__ in,
                                                   const float* __restrict__ W,
                                                   const float* __restrict__ a_src,
                                                   const float* __restrict__ a_dst,
                                                   float* __restrict__ out,
                                                   float* __restrict__ es,
                                                   float* __restrict__ ed) {
    __shared__ float Wl[FIN * 64];
    __shared__ float inl[32 * FIN];
    const int tid = threadIdx.x;
    const int n0 = blockIdx.x * 32;
    const int o = tid & 63;
    const int w = tid >> 6;

    for (int c = 0; c < NCH; ++c) {
        for (int i = tid; i < FIN * 64; i += 256) Wl[i] = W[c * FIN * 64 + i];
        for (int i = tid; i < 32 * FIN; i += 256) {
            int nl = i / FIN, k = i - nl * FIN;
            float v = in[(size_t)(n0 + nl) * (NCH * FIN) + c * FIN + k];
            if (SILU_IN) v = silu_f(v);
            inl[i] = v;
        }
        __syncthreads();

        float as = 0.f, ad = 0.f;
        if (ATT) { as = a_src[c * 64 + o]; ad = a_dst[c * 64 + o]; }

        float acc[8];
#pragma unroll
        for (int i = 0; i < 8; ++i) acc[i] = 0.f;
#pragma unroll 4
        for (int k = 0; k < FIN; ++k) {
            float wv = Wl[k * 64 + o];
#pragma unroll
            for (int i = 0; i < 8; ++i) acc[i] += inl[(w * 8 + i) * FIN + k] * wv;
        }
#pragma unroll
        for (int i = 0; i < 8; ++i) {
            int n = n0 + w * 8 + i;
            out[(size_t)n * 256 + c * 64 + o] = acc[i];
            if (ATT) {
                float vs = acc[i] * as, vd = acc[i] * ad;
#pragma unroll
                for (int off = 32; off; off >>= 1) {
                    vs += __shfl_xor(vs, off);
                    vd += __shfl_xor(vd, off);
                }
                if (o == 0) { es[n * NCH + c] = vs; ed[n * NCH + c] = vd; }
            }
        }
        __syncthreads();
    }
}

// ---------- CSR build: histogram -> hierarchical scan -> scatter ----------
__global__ void hist_kernel(const int* __restrict__ ei, int* __restrict__ cnt, int E) {
    int e = blockIdx.x * 256 + threadIdx.x;
    if (e < E) atomicAdd(&cnt[ei[E + e]], 1);
}

__global__ __launch_bounds__(256) void scan_l1_kernel(const int* __restrict__ cnt,
                                                      int* __restrict__ rowp,
                                                      int* __restrict__ bsum, int n) {
    int i = blockIdx.x * 256 + threadIdx.x;
    int l = threadIdx.x & 63, w = threadIdx.x >> 6;
    int v = (i < n) ? cnt[i] : 0;
    int incl = wave_iscan(v, l);
    __shared__ int wsum[4];
    if (l == 63) wsum[w] = incl;
    __syncthreads();
    int add = 0;
#pragma unroll
    for (int j = 0; j < 4; ++j) add += (j < w) ? wsum[j] : 0;
    if (i < n) rowp[i] = add + incl - v;
    if (threadIdx.x == 255) bsum[blockIdx.x] = add + incl;
}

__global__ __launch_bounds__(256) void scan_l2_kernel(const int* __restrict__ bsum,
                                                      int* __restrict__ boff,
                                                      int* __restrict__ rowp_n, int nb,
                                                      float* __restrict__ out_zero) {
    int i = threadIdx.x;
    if (i < S_OUT) out_zero[i] = 0.f;  // fused energies zero-init
    int l = i & 63, w = i >> 6;
    int v = (i < nb) ? bsum[i] : 0;
    int incl = wave_iscan(v, l);
    __shared__ int wsum[4];
    if (l == 63) wsum[w] = incl;
    __syncthreads();
    int add = 0;
#pragma unroll
    for (int j = 0; j < 4; ++j) add += (j < w) ? wsum[j] : 0;
    if (i < nb) boff[i] = add + incl - v;
    if (i == nb - 1) *rowp_n = add + incl;
}

__global__ __launch_bounds__(256) void scan_l3_kernel(int* __restrict__ rowp,
                                                      const int* __restrict__ boff, int n) {
    int i = blockIdx.x * 256 + threadIdx.x;
    if (i < n) rowp[i] += boff[blockIdx.x];
}

__global__ void scatter_kernel(const int* __restrict__ ei, const int* __restrict__ rowp,
                               int* __restrict__ fill, int* __restrict__ csr_src, int E) {
    int e = blockIdx.x * 256 + threadIdx.x;
    if (e < E) {
        int d = ei[E + e];
        int pos = rowp[d] + atomicAdd(&fill[d], 1);
        csr_src[pos] = ei[e];
    }
}

// ---------- fused GAT aggregation (gather side): softmax + weighted sum ----------
// one block per dst node; 4 waves = 4 channels; 64 lanes dual-role (edges / features)
template <bool SILU_OUT>
__global__ __launch_bounds__(256) void gat_gather_kernel(const int* __restrict__ rowp,
                                                         const int* __restrict__ csr_src,
                                                         const float* __restrict__ es,
                                                         const float* __restrict__ ed,
                                                         const float* __restrict__ h,
                                                         float* __restrict__ out) {
    int d = blockIdx.x;
    int c = threadIdx.x >> 6, o = threadIdx.x & 63;
    int r0 = rowp[d], r1 = rowp[d + 1];
    __shared__ int   ssrc[NCH][64];
    __shared__ float sex[NCH][64];
    float edc = ed[d * NCH + c];
    float m = -1e30f, den = 0.f, acc = 0.f;
    for (int base = r0; base < r1; base += 64) {
        int len = min(64, r1 - base);
        // phase A: lanes = edges
        float logit = -1e30f;
        int s = 0;
        if (o < len) {
            s = csr_src[base + o];
            float v = es[s * NCH + c] + edc;
            logit = v >= 0.f ? v : 0.2f * v;
        }
        float cm = logit;
#pragma unroll
        for (int off = 32; off; off >>= 1) cm = fmaxf(cm, __shfl_xor(cm, off));
        float nm = fmaxf(m, cm);
        float resc = __expf(m - nm);           // 0 on first chunk
        float ex = (o < len) ? __expf(logit - nm) : 0.f;
        float cs = ex;
#pragma unroll
        for (int off = 32; off; off >>= 1) cs += __shfl_xor(cs, off);
        den = den * resc + cs;
        acc *= resc;
        m = nm;
        ssrc[c][o] = s;
        sex[c][o] = ex;
        __syncthreads();
        // phase B: lanes = features
        for (int jj = 0; jj < len; ++jj) {
            int sj = ssrc[c][jj];
            acc += sex[c][jj] * h[(size_t)sj * 256 + c * 64 + o];
        }
        __syncthreads();
    }
    float r = acc / (den + 1e-16f);
    out[(size_t)d * 256 + c * 64 + o] = SILU_OUT ? silu_f(r) : r;
}

// ---------- MLP head: thread = (node, channel); weights via scalar (s_load) stream ----------
// c = blockIdx.y makes all weight addresses provably wave-uniform -> SGPR streams,
// so every MAC is one v_fmac_f32 (vector acc, scalar weight). t1/t2 only indexed
// in fully-unrolled loops -> registers, no scratch.
__global__ __launch_bounds__(256) void mlp_node_kernel(const float* __restrict__ in,
                                                       const float* __restrict__ W1,
                                                       const float* __restrict__ W2,
                                                       const float* __restrict__ W3,
                                                       const int* __restrict__ bat,
                                                       float* __restrict__ out) {
    const int c = blockIdx.y;                       // block-uniform
    const int node = blockIdx.x * 256 + threadIdx.x;
    const bool act = node < N_ATOMS;
    const int nn = act ? node : N_ATOMS - 1;
    const float* __restrict__ w1 = W1 + c * 4096;
    const float* __restrict__ w2 = W2 + c * 2048;
    const float* __restrict__ w3 = W3 + c * 32;
    const float* __restrict__ hp = in + (size_t)nn * 256 + c * 64;  // contiguous 256B row

    float t1[64];
#pragma unroll
    for (int o = 0; o < 64; ++o) t1[o] = 0.f;

    // layer 1: 64x64, k-chunked by float4 (loop NOT unrolled: keeps code small;
    // 64 independent acc chains hide FMA latency; next-chunk loads pipeline)
    for (int kq = 0; kq < 16; ++kq) {
        float4 h4 = *(const float4*)(hp + kq * 4);
        const float* wr = w1 + kq * 4 * 64;
#pragma unroll
        for (int o = 0; o < 64; ++o) t1[o] = fmaf(h4.x, wr[o], t1[o]);
#pragma unroll
        for (int o = 0; o < 64; ++o) t1[o] = fmaf(h4.y, wr[64 + o], t1[o]);
#pragma unroll
        for (int o = 0; o < 64; ++o) t1[o] = fmaf(h4.z, wr[128 + o], t1[o]);
#pragma unroll
        for (int o = 0; o < 64; ++o) t1[o] = fmaf(h4.w, wr[192 + o], t1[o]);
    }
#pragma unroll
    for (int o = 0; o < 64; ++o) t1[o] = silu_f(t1[o]);

    // layer 2: 64x32, fully unrolled (t1[k] must be statically indexed)
    float t2[32];
#pragma unroll
    for (int o = 0; o < 32; ++o) t2[o] = 0.f;
#pragma unroll
    for (int k = 0; k < 64; ++k) {
#pragma unroll
        for (int o = 0; o < 32; ++o) t2[o] = fmaf(t1[k], w2[k * 32 + o], t2[o]);
    }

    // layer 3: dot with w3
    float y = 0.f;
#pragma unroll
    for (int o = 0; o < 32; ++o) y = fmaf(silu_f(t2[o]), w3[o], y);

    float val = act ? y * 0.025f : 0.f;  // /sqrt(4)/20
    int b = act ? bat[nn] : 0;

    // segmented wave reduction over sorted batch ids (1-2 segments typical)
    int lane = threadIdx.x & 63;
    unsigned long long rem = __ballot(act);
    while (rem) {
        int lead = (int)__ffsll(rem) - 1;
        int bl = __shfl(b, lead);
        bool mine = act && (b == bl);
        float t = mine ? val : 0.f;
#pragma unroll
        for (int off = 32; off; off >>= 1) t += __shfl_xor(t, off);
        if (lane == lead) atomicAdd(out + bl, t);
        rem &= ~__ballot(mine);
    }
}

extern "C" void kernel_launch(void* const* d_in, const int* in_sizes, int n_in,
                              void* d_out, int out_size, void* d_ws, size_t ws_size,
                              hipStream_t stream) {
    const float* x     = (const float*)d_in[0];
    const int*   ei    = (const int*)d_in[1];
    const int*   bat   = (const int*)d_in[2];
    const float* gamma = (const float*)d_in[3];
    const float* beta  = (const float*)d_in[4];
    const float* Wc1   = (const float*)d_in[5];
    const float* as1   = (const float*)d_in[6];
    const float* ad1   = (const float*)d_in[7];
    const float* Wc2   = (const float*)d_in[8];
    const float* as2   = (const float*)d_in[9];
    const float* ad2   = (const float*)d_in[10];
    const float* Wn1   = (const float*)d_in[11];
    const float* Wn2   = (const float*)d_in[12];
    const float* Wout  = (const float*)d_in[13];
    float* out = (float*)d_out;

    // workspace layout (floats)
    float* A    = (float*)d_ws;            // 10.24M: LN out [N,C,128]; reused for conv outs
    float* B    = A + 10240000;            // 5.12M : proj output h [N,C,64]
    float* es   = B + 5120000;             // 80k
    float* ed   = es + 80000;              // 80k
    int* rowp   = (int*)(ed + 80000);      // 20001 (pad 20004)
    int* cnt    = rowp + 20004;            // 20000
    int* fillc  = cnt + 20000;             // 20000
    int* csr    = fillc + 20000;           // 400000
    int* bsum   = csr + 400000;            // 128
    int* boff   = bsum + 128;              // 128
    float* C1   = A;                       // conv1 out [N,C,64]
    float* C2   = A + 5120000;             // conv2 out (silu'd) [N,C,64]

    dim3 blk(256);
    const int NB = (N_ATOMS + 255) / 256;  // 79

    // ---- CSR build (graph is shared by both convs) ----
    fill_kernel<<<80, blk, 0, stream>>>((float*)cnt, 40000, 0.f);  // cnt + fillc (adjacent)
    hist_kernel<<<(N_EDGES + 255) / 256, blk, 0, stream>>>(ei, cnt, N_EDGES);
    scan_l1_kernel<<<NB, blk, 0, stream>>>(cnt, rowp, bsum, N_ATOMS);
    scan_l2_kernel<<<1, blk, 0, stream>>>(bsum, boff, rowp + N_ATOMS, NB, out);
    scan_l3_kernel<<<NB, blk, 0, stream>>>(rowp, boff, N_ATOMS);
    scatter_kernel<<<(N_EDGES + 255) / 256, blk, 0, stream>>>(ei, rowp, fillc, csr, N_EDGES);

    // ---- LayerNorm ----
    ln_kernel<<<N_ATOMS * NCH / 4, blk, 0, stream>>>(x, gamma, beta, A);

    // ---- conv1 ----
    proj_kernel<128, false, true><<<N_ATOMS / 32, blk, 0, stream>>>(A, Wc1, as1, ad1, B, es, ed);
    gat_gather_kernel<false><<<N_ATOMS, blk, 0, stream>>>(rowp, csr, es, ed, B, C1);

    // ---- conv2 (silu fused on load; silu fused on output for MLP) ----
    proj_kernel<64, true, true><<<N_ATOMS / 32, blk, 0, stream>>>(C1, Wc2, as2, ad2, B, es, ed);
    gat_gather_kernel<true><<<N_ATOMS, blk, 0, stream>>>(rowp, csr, es, ed, B, C2);

    // ---- MLP head: per-(node,channel) threads, scalar weight streams ----
    mlp_node_kernel<<<dim3(NB, NCH), blk, 0, stream>>>(C2, Wn1, Wn2, Wout, bat, out);
}

// Round 8
// 318.024 us; speedup vs baseline: 1.3073x; 1.0509x over previous
//
#include <hip/hip_runtime.h>
#include <hip/hip_bf16.h>

// Problem constants (match reference)
#define N_ATOMS 20000
#define N_EDGES 400000
#define NCH 4
#define F_IN 128
#define S_OUT 32

// ---------- helpers ----------
__device__ __forceinline__ float silu_f(float v) { return v / (1.f + __expf(-v)); }

__device__ __forceinline__ int wave_iscan(int v, int l) {
#pragma unroll
    for (int off = 1; off < 64; off <<= 1) {
        int t = __shfl_up(v, off);
        if (l >= off) v += t;
    }
    return v;
}

// ---------- fill ----------
__global__ void fill_kernel(float* __restrict__ p, int n, float v) {
    int i = blockIdx.x * blockDim.x + threadIdx.x;
    int stride = gridDim.x * blockDim.x;
    for (; i < n; i += stride) p[i] = v;
}

// ---------- CSR build: histogram -> hierarchical scan -> scatter ----------
__global__ void hist_kernel(const int* __restrict__ ei, int* __restrict__ cnt, int E) {
    int e = blockIdx.x * 256 + threadIdx.x;
    if (e < E) atomicAdd(&cnt[ei[E + e]], 1);
}

__global__ __launch_bounds__(256) void scan_l1_kernel(const int* __restrict__ cnt,
                                                      int* __restrict__ rowp,
                                                      int* __restrict__ bsum, int n) {
    int i = blockIdx.x * 256 + threadIdx.x;
    int l = threadIdx.x & 63, w = threadIdx.x >> 6;
    int v = (i < n) ? cnt[i] : 0;
    int incl = wave_iscan(v, l);
    __shared__ int wsum[4];
    if (l == 63) wsum[w] = incl;
    __syncthreads();
    int add = 0;
#pragma unroll
    for (int j = 0; j < 4; ++j) add += (j < w) ? wsum[j] : 0;
    if (i < n) rowp[i] = add + incl - v;
    if (threadIdx.x == 255) bsum[blockIdx.x] = add + incl;
}

__global__ __launch_bounds__(256) void scan_l2_kernel(const int* __restrict__ bsum,
                                                      int* __restrict__ boff,
                                                      int* __restrict__ rowp_n, int nb,
                                                      float* __restrict__ out_zero) {
    int i = threadIdx.x;
    if (i < S_OUT) out_zero[i] = 0.f;  // fused energies zero-init
    int l = i & 63, w = i >> 6;
    int v = (i < nb) ? bsum[i] : 0;
    int incl = wave_iscan(v, l);
    __shared__ int wsum[4];
    if (l == 63) wsum[w] = incl;
    __syncthreads();
    int add = 0;
#pragma unroll
    for (int j = 0; j < 4; ++j) add += (j < w) ? wsum[j] : 0;
    if (i < nb) boff[i] = add + incl - v;
    if (i == nb - 1) *rowp_n = add + incl;
}

__global__ __launch_bounds__(256) void scan_l3_kernel(int* __restrict__ rowp,
                                                      const int* __restrict__ boff, int n) {
    int i = blockIdx.x * 256 + threadIdx.x;
    if (i < n) rowp[i] += boff[blockIdx.x];
}

__global__ void scatter_kernel(const int* __restrict__ ei, const int* __restrict__ rowp,
                               int* __restrict__ fill, int* __restrict__ csr_src, int E) {
    int e = blockIdx.x * 256 + threadIdx.x;
    if (e < E) {
        int d = ei[E + e];
        int pos = rowp[d] + atomicAdd(&fill[d], 1);
        csr_src[pos] = ei[e];
    }
}

// ---------- conv1 projection with fused LayerNorm ----------
// thread = node, c = blockIdx.y. Weights/gamma/beta/a-vecs are wave-uniform ->
// scalar (s_load) streams; accumulators t[64] in registers (static indexing only).
__global__ __launch_bounds__(256) void proj1_kernel(const float* __restrict__ x,
                                                    const float* __restrict__ gamma,
                                                    const float* __restrict__ beta,
                                                    const float* __restrict__ W,
                                                    const float* __restrict__ a_src,
                                                    const float* __restrict__ a_dst,
                                                    float* __restrict__ out,
                                                    float* __restrict__ es,
                                                    float* __restrict__ ed) {
    const int c = blockIdx.y;
    const int node = blockIdx.x * 256 + threadIdx.x;
    const bool act = node < N_ATOMS;
    const int nn = act ? node : N_ATOMS - 1;
    const float* __restrict__ xr = x + (size_t)nn * (NCH * F_IN) + c * F_IN;
    const float* __restrict__ w0 = W + c * (F_IN * 64);

    // pass 1: mean / var over the 128-row
    float s = 0.f, sq = 0.f;
    for (int kq = 0; kq < 32; ++kq) {
        float4 v = *(const float4*)(xr + kq * 4);
        s += (v.x + v.y) + (v.z + v.w);
        sq += (v.x * v.x + v.y * v.y) + (v.z * v.z + v.w * v.w);
    }
    float mu = s * (1.f / 128.f);
    float rs = rsqrtf(sq * (1.f / 128.f) - mu * mu + 1e-5f);

    float t[64];
#pragma unroll
    for (int o = 0; o < 64; ++o) t[o] = 0.f;

    // pass 2: normalize on the fly + GEMV (scalar weights, 64 indep chains)
    for (int kq = 0; kq < 32; ++kq) {
        float4 v = *(const float4*)(xr + kq * 4);
        const float* g = gamma + kq * 4;
        const float* b = beta + kq * 4;
        float h0 = (v.x - mu) * rs * g[0] + b[0];
        float h1 = (v.y - mu) * rs * g[1] + b[1];
        float h2 = (v.z - mu) * rs * g[2] + b[2];
        float h3 = (v.w - mu) * rs * g[3] + b[3];
        const float* wr = w0 + kq * 4 * 64;
#pragma unroll
        for (int o = 0; o < 64; ++o) t[o] = fmaf(h0, wr[o], t[o]);
#pragma unroll
        for (int o = 0; o < 64; ++o) t[o] = fmaf(h1, wr[64 + o], t[o]);
#pragma unroll
        for (int o = 0; o < 64; ++o) t[o] = fmaf(h2, wr[128 + o], t[o]);
#pragma unroll
        for (int o = 0; o < 64; ++o) t[o] = fmaf(h3, wr[192 + o], t[o]);
    }

    // attention dots (uniform a-vectors -> per-thread dots, no shuffles)
    const float* av = a_src + c * 64;
    const float* bv = a_dst + c * 64;
    float esv = 0.f, edv = 0.f;
#pragma unroll
    for (int o = 0; o < 64; ++o) { esv = fmaf(t[o], av[o], esv); edv = fmaf(t[o], bv[o], edv); }

    if (act) {
        float* orow = out + (size_t)node * 256 + c * 64;
#pragma unroll
        for (int oq = 0; oq < 16; ++oq) {
            float4 v = make_float4(t[oq * 4], t[oq * 4 + 1], t[oq * 4 + 2], t[oq * 4 + 3]);
            *(float4*)(orow + oq * 4) = v;
        }
        es[node * NCH + c] = esv;
        ed[node * NCH + c] = edv;
    }
}

// ---------- conv2 projection (input already silu'd by gather1) ----------
__global__ __launch_bounds__(256) void proj2_kernel(const float* __restrict__ in,
                                                    const float* __restrict__ W,
                                                    const float* __restrict__ a_src,
                                                    const float* __restrict__ a_dst,
                                                    float* __restrict__ out,
                                                    float* __restrict__ es,
                                                    float* __restrict__ ed) {
    const int c = blockIdx.y;
    const int node = blockIdx.x * 256 + threadIdx.x;
    const bool act = node < N_ATOMS;
    const int nn = act ? node : N_ATOMS - 1;
    const float* __restrict__ hr = in + (size_t)nn * 256 + c * 64;
    const float* __restrict__ w0 = W + c * (64 * 64);

    float t[64];
#pragma unroll
    for (int o = 0; o < 64; ++o) t[o] = 0.f;

    for (int kq = 0; kq < 16; ++kq) {
        float4 v = *(const float4*)(hr + kq * 4);
        const float* wr = w0 + kq * 4 * 64;
#pragma unroll
        for (int o = 0; o < 64; ++o) t[o] = fmaf(v.x, wr[o], t[o]);
#pragma unroll
        for (int o = 0; o < 64; ++o) t[o] = fmaf(v.y, wr[64 + o], t[o]);
#pragma unroll
        for (int o = 0; o < 64; ++o) t[o] = fmaf(v.z, wr[128 + o], t[o]);
#pragma unroll
        for (int o = 0; o < 64; ++o) t[o] = fmaf(v.w, wr[192 + o], t[o]);
    }

    const float* av = a_src + c * 64;
    const float* bv = a_dst + c * 64;
    float esv = 0.f, edv = 0.f;
#pragma unroll
    for (int o = 0; o < 64; ++o) { esv = fmaf(t[o], av[o], esv); edv = fmaf(t[o], bv[o], edv); }

    if (act) {
        float* orow = out + (size_t)node * 256 + c * 64;
#pragma unroll
        for (int oq = 0; oq < 16; ++oq) {
            float4 v = make_float4(t[oq * 4], t[oq * 4 + 1], t[oq * 4 + 2], t[oq * 4 + 3]);
            *(float4*)(orow + oq * 4) = v;
        }
        es[node * NCH + c] = esv;
        ed[node * NCH + c] = edv;
    }
}

// ---------- fused GAT aggregation (gather side): softmax + weighted sum ----------
// one block per dst node; 4 waves = 4 channels; 64 lanes dual-role (edges / features)
template <bool SILU_OUT>
__global__ __launch_bounds__(256) void gat_gather_kernel(const int* __restrict__ rowp,
                                                         const int* __restrict__ csr_src,
                                                         const float* __restrict__ es,
                                                         const float* __restrict__ ed,
                                                         const float* __restrict__ h,
                                                         float* __restrict__ out) {
    int d = blockIdx.x;
    int c = threadIdx.x >> 6, o = threadIdx.x & 63;
    int r0 = rowp[d], r1 = rowp[d + 1];
    __shared__ int   ssrc[NCH][64];
    __shared__ float sex[NCH][64];
    float edc = ed[d * NCH + c];
    float m = -1e30f, den = 0.f, acc = 0.f;
    for (int base = r0; base < r1; base += 64) {
        int len = min(64, r1 - base);
        // phase A: lanes = edges
        float logit = -1e30f;
        int s = 0;
        if (o < len) {
            s = csr_src[base + o];
            float v = es[s * NCH + c] + edc;
            logit = v >= 0.f ? v : 0.2f * v;
        }
        float cm = logit;
#pragma unroll
        for (int off = 32; off; off >>= 1) cm = fmaxf(cm, __shfl_xor(cm, off));
        float nm = fmaxf(m, cm);
        float resc = __expf(m - nm);           // 0 on first chunk
        float ex = (o < len) ? __expf(logit - nm) : 0.f;
        float cs = ex;
#pragma unroll
        for (int off = 32; off; off >>= 1) cs += __shfl_xor(cs, off);
        den = den * resc + cs;
        acc *= resc;
        m = nm;
        ssrc[c][o] = s;
        sex[c][o] = ex;
        __syncthreads();
        // phase B: lanes = features
        for (int jj = 0; jj < len; ++jj) {
            int sj = ssrc[c][jj];
            acc += sex[c][jj] * h[(size_t)sj * 256 + c * 64 + o];
        }
        __syncthreads();
    }
    float r = acc / (den + 1e-16f);
    out[(size_t)d * 256 + c * 64 + o] = SILU_OUT ? silu_f(r) : r;
}

// ---------- MLP head: thread = (node, channel); weights via scalar (s_load) stream ----------
__global__ __launch_bounds__(256) void mlp_node_kernel(const float* __restrict__ in,
                                                       const float* __restrict__ W1,
                                                       const float* __restrict__ W2,
                                                       const float* __restrict__ W3,
                                                       const int* __restrict__ bat,
                                                       float* __restrict__ out) {
    const int c = blockIdx.y;                       // block-uniform
    const int node = blockIdx.x * 256 + threadIdx.x;
    const bool act = node < N_ATOMS;
    const int nn = act ? node : N_ATOMS - 1;
    const float* __restrict__ w1 = W1 + c * 4096;
    const float* __restrict__ w2 = W2 + c * 2048;
    const float* __restrict__ w3 = W3 + c * 32;
    const float* __restrict__ hp = in + (size_t)nn * 256 + c * 64;  // contiguous 256B row

    float t1[64];
#pragma unroll
    for (int o = 0; o < 64; ++o) t1[o] = 0.f;

    for (int kq = 0; kq < 16; ++kq) {
        float4 h4 = *(const float4*)(hp + kq * 4);
        const float* wr = w1 + kq * 4 * 64;
#pragma unroll
        for (int o = 0; o < 64; ++o) t1[o] = fmaf(h4.x, wr[o], t1[o]);
#pragma unroll
        for (int o = 0; o < 64; ++o) t1[o] = fmaf(h4.y, wr[64 + o], t1[o]);
#pragma unroll
        for (int o = 0; o < 64; ++o) t1[o] = fmaf(h4.z, wr[128 + o], t1[o]);
#pragma unroll
        for (int o = 0; o < 64; ++o) t1[o] = fmaf(h4.w, wr[192 + o], t1[o]);
    }
#pragma unroll
    for (int o = 0; o < 64; ++o) t1[o] = silu_f(t1[o]);

    float t2[32];
#pragma unroll
    for (int o = 0; o < 32; ++o) t2[o] = 0.f;
#pragma unroll
    for (int k = 0; k < 64; ++k) {
#pragma unroll
        for (int o = 0; o < 32; ++o) t2[o] = fmaf(t1[k], w2[k * 32 + o], t2[o]);
    }

    float y = 0.f;
#pragma unroll
    for (int o = 0; o < 32; ++o) y = fmaf(silu_f(t2[o]), w3[o], y);

    float val = act ? y * 0.025f : 0.f;  // /sqrt(4)/20
    int b = act ? bat[nn] : 0;

    // segmented wave reduction over sorted batch ids (1-2 segments typical)
    int lane = threadIdx.x & 63;
    unsigned long long rem = __ballot(act);
    while (rem) {
        int lead = (int)__ffsll(rem) - 1;
        int bl = __shfl(b, lead);
        bool mine = act && (b == bl);
        float t = mine ? val : 0.f;
#pragma unroll
        for (int off = 32; off; off >>= 1) t += __shfl_xor(t, off);
        if (lane == lead) atomicAdd(out + bl, t);
        rem &= ~__ballot(mine);
    }
}

extern "C" void kernel_launch(void* const* d_in, const int* in_sizes, int n_in,
                              void* d_out, int out_size, void* d_ws, size_t ws_size,
                              hipStream_t stream) {
    const float* x     = (const float*)d_in[0];
    const int*   ei    = (const int*)d_in[1];
    const int*   bat   = (const int*)d_in[2];
    const float* gamma = (const float*)d_in[3];
    const float* beta  = (const float*)d_in[4];
    const float* Wc1   = (const float*)d_in[5];
    const float* as1   = (const float*)d_in[6];
    const float* ad1   = (const float*)d_in[7];
    const float* Wc2   = (const float*)d_in[8];
    const float* as2   = (const float*)d_in[9];
    const float* ad2   = (const float*)d_in[10];
    const float* Wn1   = (const float*)d_in[11];
    const float* Wn2   = (const float*)d_in[12];
    const float* Wout  = (const float*)d_in[13];
    float* out = (float*)d_out;

    // workspace layout (floats)
    float* A    = (float*)d_ws;            // reused for conv outs
    float* B    = A + 10240000;            // proj output h [N,C,64]
    float* es   = B + 5120000;             // 80k
    float* ed   = es + 80000;              // 80k
    int* rowp   = (int*)(ed + 80000);      // 20001 (pad 20004)
    int* cnt    = rowp + 20004;            // 20000
    int* fillc  = cnt + 20000;             // 20000
    int* csr    = fillc + 20000;           // 400000
    int* bsum   = csr + 400000;            // 128
    int* boff   = bsum + 128;              // 128
    float* C1   = A;                       // conv1 out (silu'd) [N,C,64]
    float* C2   = A + 5120000;             // conv2 out (silu'd) [N,C,64]

    dim3 blk(256);
    const int NB = (N_ATOMS + 255) / 256;  // 79

    // ---- CSR build (graph is shared by both convs) ----
    fill_kernel<<<80, blk, 0, stream>>>((float*)cnt, 40000, 0.f);  // cnt + fillc (adjacent)
    hist_kernel<<<(N_EDGES + 255) / 256, blk, 0, stream>>>(ei, cnt, N_EDGES);
    scan_l1_kernel<<<NB, blk, 0, stream>>>(cnt, rowp, bsum, N_ATOMS);
    scan_l2_kernel<<<1, blk, 0, stream>>>(bsum, boff, rowp + N_ATOMS, NB, out);
    scan_l3_kernel<<<NB, blk, 0, stream>>>(rowp, boff, N_ATOMS);
    scatter_kernel<<<(N_EDGES + 255) / 256, blk, 0, stream>>>(ei, rowp, fillc, csr, N_EDGES);

    // ---- conv1 (LN fused into proj) ----
    proj1_kernel<<<dim3(NB, NCH), blk, 0, stream>>>(x, gamma, beta, Wc1, as1, ad1, B, es, ed);
    gat_gather_kernel<true><<<N_ATOMS, blk, 0, stream>>>(rowp, csr, es, ed, B, C1);  // silu'd

    // ---- conv2 ----
    proj2_kernel<<<dim3(NB, NCH), blk, 0, stream>>>(C1, Wc2, as2, ad2, B, es, ed);
    gat_gather_kernel<true><<<N_ATOMS, blk, 0, stream>>>(rowp, csr, es, ed, B, C2);  // silu'd

    // ---- MLP head: per-(node,channel) threads, scalar weight streams ----
    mlp_node_kernel<<<dim3(NB, NCH), blk, 0, stream>>>(C2, Wn1, Wn2, Wout, bat, out);
}